// Round 4
// baseline (525.566 us; speedup 1.0000x reference)
//
#include <hip/hip_runtime.h>

#define NNODES 100000

// ---- bf16 helpers (storage only; all accumulation fp32) ----
__device__ __forceinline__ float bf2f(unsigned short u) {
    unsigned int v = ((unsigned int)u) << 16;
    return __builtin_bit_cast(float, v);
}
__device__ __forceinline__ unsigned short f2bf(float f) {
    unsigned int u = __builtin_bit_cast(unsigned int, f);
    u += 0x7FFF + ((u >> 16) & 1);   // round-to-nearest-even
    return (unsigned short)(u >> 16);
}

// ================= build: 4 sub-chains per dst + in-degree counts =================
// head[(dst<<2)|(e&3)] = latest edge; nx[e] = (next_edge, src). counts[dst] += 1.

__global__ __launch_bounds__(256) void build_kernel(const int* __restrict__ ei, int E,
                                                    int* __restrict__ head,
                                                    int2* __restrict__ nx,
                                                    int* __restrict__ counts) {
    int e = blockIdx.x * 256 + threadIdx.x;
    if (e >= E) return;
    int src = ei[e];
    int dst = ei[E + e];
    atomicAdd(&counts[dst], 1);
    int old = atomicExch(&head[(dst << 2) | (e & 3)], e);
    nx[e] = make_int2(old, src);           // coalesced 8B write
}

__global__ __launch_bounds__(256) void dinv_kernel(const int* __restrict__ counts,
                                                   float* __restrict__ dinv, int N) {
    int i = blockIdx.x * 256 + threadIdx.x;
    if (i < N) dinv[i] = rsqrtf((float)counts[i] + 1.0f);  // +1 self loop
}

// s_acc[dst] += dinv[src]  (400 KB L2-resident fp32 atomics)
__global__ __launch_bounds__(256) void s_edge_kernel(const int* __restrict__ ei, int E,
                                                     const float* __restrict__ dinv,
                                                     float* __restrict__ s_acc) {
    int e = blockIdx.x * 256 + threadIdx.x;
    if (e < E) atomicAdd(&s_acc[ei[E + e]], dinv[ei[e]]);
}

// ================= tiny GEMMs: W12 = W1 @ W2 (128x64), bW2 = b1 @ W2 =================

__global__ __launch_bounds__(256) void w12_kernel(const float* __restrict__ W1,
                                                  const float* __restrict__ b1,
                                                  const float* __restrict__ W2,
                                                  float* __restrict__ W12,
                                                  float* __restrict__ bW2) {
    int j = threadIdx.x % 64;
    int r = threadIdx.x / 64;  // 0..3
    if (blockIdx.x < 32) {
        int i = blockIdx.x * 4 + r;
        float acc = 0.f;
        for (int k = 0; k < 128; ++k) acc += W1[i * 128 + k] * W2[k * 64 + j];
        W12[i * 64 + j] = acc;
    } else if (r == 0) {
        float acc = 0.f;
        for (int k = 0; k < 128; ++k) acc += b1[k] * W2[k * 64 + j];
        bW2[j] = acc;
    }
}

// ========== GEMM: Ybf[i,:] = bf16( dinv[i] * (X[i,:] @ W) ), K=128, OD=64 ==========

__global__ __launch_bounds__(256) void gemm_scale_bf(const float* __restrict__ X,
                                                     const float* __restrict__ W,
                                                     const float* __restrict__ dinv,
                                                     unsigned short* __restrict__ Ybf, int N) {
    constexpr int K = 128;
    constexpr int KP = K + 4;
    constexpr int OD = 64;
    constexpr int JG = OD / 4;     // 16
    constexpr int TR = 256 / JG;   // 16
    constexpr int ROWS = TR * 4;   // 64

    __shared__ float sW[K * OD];
    __shared__ float sX[ROWS * KP];

    const int tid = threadIdx.x;

    for (int i = tid; i < K * OD / 4; i += 256)
        ((float4*)sW)[i] = ((const float4*)W)[i];

    const int jg = tid % JG;
    const int tr = tid / JG;
    const int r0 = tr * 4;
    const int base = blockIdx.x * ROWS;

    const int k4 = (tid & 31) * 4;
    for (int rl = tid >> 5; rl < ROWS; rl += 8) {
        int row = base + rl;
        float4 v = make_float4(0.f, 0.f, 0.f, 0.f);
        if (row < N) v = *(const float4*)(X + (size_t)row * K + k4);
        *(float4*)(sX + rl * KP + k4) = v;
    }
    __syncthreads();

    float acc[4][4] = {{0.f}};
#pragma unroll 8
    for (int k = 0; k < K; ++k) {
        float4 w = *(const float4*)(sW + k * OD + jg * 4);
        float x0 = sX[(r0 + 0) * KP + k];
        float x1 = sX[(r0 + 1) * KP + k];
        float x2 = sX[(r0 + 2) * KP + k];
        float x3 = sX[(r0 + 3) * KP + k];
        acc[0][0] += x0 * w.x; acc[0][1] += x0 * w.y; acc[0][2] += x0 * w.z; acc[0][3] += x0 * w.w;
        acc[1][0] += x1 * w.x; acc[1][1] += x1 * w.y; acc[1][2] += x1 * w.z; acc[1][3] += x1 * w.w;
        acc[2][0] += x2 * w.x; acc[2][1] += x2 * w.y; acc[2][2] += x2 * w.z; acc[2][3] += x2 * w.w;
        acc[3][0] += x3 * w.x; acc[3][1] += x3 * w.y; acc[3][2] += x3 * w.z; acc[3][3] += x3 * w.w;
    }

#pragma unroll
    for (int i = 0; i < 4; ++i) {
        int row = base + r0 + i;
        if (row < N) {
            float sc = dinv[row];
            ushort4 o;
            o.x = f2bf(acc[i][0] * sc);
            o.y = f2bf(acc[i][1] * sc);
            o.z = f2bf(acc[i][2] * sc);
            o.w = f2bf(acc[i][3] * sc);
            *(ushort4*)(Ybf + (size_t)row * OD + jg * 4) = o;  // 8B store
        }
    }
}

// ========== aggregate over 4 concurrent sub-chains, 16 threads/node ==========
// FINAL=false: Zbf_i = bf16( dinv_i^2 * (Y_i + sum_src Y_src) )
// FINAL=true : out_i = dinv_i * (Y_i + sum_src Y_src) + s_i*bW2 + b2,
//              s_i = dinv_i*(dinv_i + s_acc_i)

template <bool FINAL>
__global__ __launch_bounds__(256) void aggregate4(const int* __restrict__ head,
                                                  const int2* __restrict__ nx,
                                                  const unsigned short* __restrict__ Ybf,
                                                  const float* __restrict__ dinv,
                                                  const float* __restrict__ s_acc,
                                                  const float* __restrict__ bW2,
                                                  const float* __restrict__ b2,
                                                  unsigned short* __restrict__ out_bf,
                                                  float* __restrict__ out_f, int N) {
    int node = blockIdx.x * 16 + (threadIdx.x >> 4);
    if (node >= N) return;
    int c4 = (threadIdx.x & 15) * 4;

    ushort4 sv = *(const ushort4*)(Ybf + (size_t)node * 64 + c4);  // self loop
    float ax = bf2f(sv.x), ay = bf2f(sv.y), az = bf2f(sv.z), aw = bf2f(sv.w);

    int cur0 = head[(node << 2) | 0];
    int cur1 = head[(node << 2) | 1];
    int cur2 = head[(node << 2) | 2];
    int cur3 = head[(node << 2) | 3];

    // edge ids are < 2^30, so AND == -1 iff all four chains are done
    while ((cur0 & cur1 & cur2 & cur3) != -1) {
        int2 t0, t1, t2, t3;
        if (cur0 >= 0) t0 = nx[cur0];   // same addr across the 16 lanes -> broadcast
        if (cur1 >= 0) t1 = nx[cur1];
        if (cur2 >= 0) t2 = nx[cur2];
        if (cur3 >= 0) t3 = nx[cur3];
        if (cur0 >= 0) {
            ushort4 v = *(const ushort4*)(Ybf + (size_t)t0.y * 64 + c4);
            ax += bf2f(v.x); ay += bf2f(v.y); az += bf2f(v.z); aw += bf2f(v.w);
            cur0 = t0.x;
        }
        if (cur1 >= 0) {
            ushort4 v = *(const ushort4*)(Ybf + (size_t)t1.y * 64 + c4);
            ax += bf2f(v.x); ay += bf2f(v.y); az += bf2f(v.z); aw += bf2f(v.w);
            cur1 = t1.x;
        }
        if (cur2 >= 0) {
            ushort4 v = *(const ushort4*)(Ybf + (size_t)t2.y * 64 + c4);
            ax += bf2f(v.x); ay += bf2f(v.y); az += bf2f(v.z); aw += bf2f(v.w);
            cur2 = t2.x;
        }
        if (cur3 >= 0) {
            ushort4 v = *(const ushort4*)(Ybf + (size_t)t3.y * 64 + c4);
            ax += bf2f(v.x); ay += bf2f(v.y); az += bf2f(v.z); aw += bf2f(v.w);
            cur3 = t3.x;
        }
    }

    float di = dinv[node];
    if (FINAL) {
        float si = di * (di + s_acc[node]);
        float4 bb = *(const float4*)(bW2 + c4);
        float4 b = *(const float4*)(b2 + c4);
        float4 o;
        o.x = di * ax + si * bb.x + b.x;
        o.y = di * ay + si * bb.y + b.y;
        o.z = di * az + si * bb.z + b.z;
        o.w = di * aw + si * bb.w + b.w;
        *(float4*)(out_f + (size_t)node * 64 + c4) = o;
    } else {
        float d2 = di * di;
        ushort4 o;
        o.x = f2bf(d2 * ax);
        o.y = f2bf(d2 * ay);
        o.z = f2bf(d2 * az);
        o.w = f2bf(d2 * aw);
        *(ushort4*)(out_bf + (size_t)node * 64 + c4) = o;
    }
}

// ================================ launch ================================

extern "C" void kernel_launch(void* const* d_in, const int* in_sizes, int n_in,
                              void* d_out, int out_size, void* d_ws, size_t ws_size,
                              hipStream_t stream) {
    const float* x  = (const float*)d_in[0];   // [N,128]
    const int*   ei = (const int*)d_in[1];     // [2,E] int32
    const float* W1 = (const float*)d_in[2];   // [128,128]
    const float* b1 = (const float*)d_in[3];   // [128]
    const float* W2 = (const float*)d_in[4];   // [128,64]
    const float* b2 = (const float*)d_in[5];   // [64]
    float* out = (float*)d_out;                // [N,64]

    const int N = NNODES;
    const int E = in_sizes[1] / 2;

    // workspace layout (floats): dinv N | s_acc N | counts N | head 4N | W12 8192 |
    //                            bW2 64 | ybf 32N | zbf 32N | nx (E int2)
    float* ws    = (float*)d_ws;
    float* dinv  = ws;
    float* s_acc = dinv + N;
    int*   counts= (int*)(s_acc + N);
    int*   head  = counts + N;
    float* W12   = (float*)(head + 4 * (size_t)N);
    float* bW2   = W12 + 8192;
    unsigned short* ybf = (unsigned short*)(bW2 + 64);
    unsigned short* zbf = ybf + (size_t)N * 64;
    int2*  nx    = (int2*)(zbf + (size_t)N * 64);   // offset 71N+8256 floats: 8B-aligned

    // zero s_acc + counts (adjacent), head = -1
    hipMemsetAsync(s_acc, 0, 2 * (size_t)N * sizeof(int), stream);
    hipMemsetAsync(head, 0xFF, 4 * (size_t)N * sizeof(int), stream);

    build_kernel<<<(E + 255) / 256, 256, 0, stream>>>(ei, E, head, nx, counts);
    w12_kernel<<<33, 256, 0, stream>>>(W1, b1, W2, W12, bW2);
    dinv_kernel<<<(N + 255) / 256, 256, 0, stream>>>(counts, dinv, N);
    s_edge_kernel<<<(E + 255) / 256, 256, 0, stream>>>(ei, E, dinv, s_acc);

    // out = S^2 (X @ W12) + (S 1) (x) (b1@W2) + b2
    gemm_scale_bf<<<(N + 63) / 64, 256, 0, stream>>>(x, W12, dinv, ybf, N);
    aggregate4<false><<<(N + 15) / 16, 256, 0, stream>>>(head, nx, ybf, dinv, nullptr, nullptr, nullptr, zbf, nullptr, N);
    aggregate4<true><<<(N + 15) / 16, 256, 0, stream>>>(head, nx, zbf, dinv, s_acc, bW2, b2, nullptr, out, N);
}